// Round 11
// baseline (179.609 us; speedup 1.0000x reference)
//
#include <hip/hip_runtime.h>

#define IMG_H 512
#define IMG_W 512
#define BAND   58   // output columns per wave (64 lanes - 2*3 halo)
#define STRIPH 64   // output rows per wave

__global__ __launch_bounds__(64)
void edge_wave_kernel(const float* __restrict__ in, float* __restrict__ out) {
    const int band = blockIdx.x;
    const int y0   = blockIdx.y * STRIPH;
    const int img  = blockIdx.z;
    const int lane = threadIdx.x;

    // column handled by this lane (gray space), image-edge reflected, fixed per lane
    const int col = band * BAND - 3 + lane;
    int rc = col < 0 ? -col : col;
    rc = rc >= IMG_W ? (2 * IMG_W - 2 - rc) : rc;
    const bool valid = (lane >= 3) && (lane < 3 + BAND) && (col < IMG_W);

    const float* src = in + (size_t)img * (IMG_H * IMG_W * 3) + (size_t)rc * 3;
    float* dst = out + (size_t)img * (IMG_H * IMG_W) + (size_t)y0 * IMG_W + col;

    const float wr = 0.2989f, wg = 0.5870f, wb = 0.1140f;
    // composed (sobel-smooth ∘ gauss) symmetric 7-tap: [c3,c2,c1,c0,c1,c2,c3]
    const float c0 = 1.05192494f, c1 = 0.87992161f, c2 = 0.47403752f, c3 = 0.12007838f;
    // composed (sobel-deriv ∘ gauss) antisym 7-tap: [-a3,-a2,-a1,0,a1,a2,a3]
    const float a1 = 0.17200333f, a2 = 0.23388076f, a3 = 0.12007838f;

    float w[7];  // rolling gray window, slot = local_gray_row % 7 (all indices compile-time)

    // gray value for strip-local gray-row l (image row y0-3+l, reflected at image edges)
    auto grayrow = [&](int l) -> float {
        int y = y0 - 3 + l;
        y = y < 0 ? -y : y;
        y = y >= IMG_H ? (2 * IMG_H - 2 - y) : y;
        const float* p = src + (size_t)y * (IMG_W * 3);
        return p[0] * wr + p[1] * wg + p[2] * wb;
    };

    // emit output strip-row r; window top (gray row r) lives in slot o (compile-time)
    auto emit = [&](int r, int o) {
        const float wA = w[o % 7],       wB = w[(o + 1) % 7], wC = w[(o + 2) % 7],
                    wD = w[(o + 3) % 7], wE = w[(o + 4) % 7], wF = w[(o + 5) % 7],
                    wG = w[(o + 6) % 7];
        const float v1 = c3 * (wA + wG) + c2 * (wB + wF) + c1 * (wC + wE) + c0 * wD;
        const float v2 = a3 * (wG - wA) + a2 * (wF - wB) + a1 * (wE - wC);

        const float v1m1 = __shfl_up(v1, 1, 64), v1p1 = __shfl_down(v1, 1, 64);
        const float v1m2 = __shfl_up(v1, 2, 64), v1p2 = __shfl_down(v1, 2, 64);
        const float v1m3 = __shfl_up(v1, 3, 64), v1p3 = __shfl_down(v1, 3, 64);
        const float v2m1 = __shfl_up(v2, 1, 64), v2p1 = __shfl_down(v2, 1, 64);
        const float v2m2 = __shfl_up(v2, 2, 64), v2p2 = __shfl_down(v2, 2, 64);
        const float v2m3 = __shfl_up(v2, 3, 64), v2p3 = __shfl_down(v2, 3, 64);

        const float sx = a1 * (v1p1 - v1m1) + a2 * (v1p2 - v1m2) + a3 * (v1p3 - v1m3);
        const float sy = c0 * v2 + c1 * (v2p1 + v2m1) + c2 * (v2p2 + v2m2) + c3 * (v2p3 + v2m3);
        const float m2 = sx * sx + sy * sy;
        if (valid) dst[(size_t)r * IMG_W] = (m2 > 900.0f) ? 1.0f : 0.0f;
    };

    // warm-up: fill window with gray rows 0..6, emit output row 0
    #pragma unroll
    for (int l = 0; l < 7; ++l) w[l] = grayrow(l);
    emit(0, 0);

    // steady state: 9 chunks x 7 rows (gray rows 7..69 -> output rows 1..63)
    for (int c = 0; c < 9; ++c) {
        const int lb = 7 * c + 7;
        #pragma unroll
        for (int k = 0; k < 7; ++k) {
            w[k] = grayrow(lb + k);          // slot (lb+k) % 7 == k
            emit(7 * c + 1 + k, (k + 1) % 7);
        }
    }
}

extern "C" void kernel_launch(void* const* d_in, const int* in_sizes, int n_in,
                              void* d_out, int out_size, void* d_ws, size_t ws_size,
                              hipStream_t stream) {
    const float* in = (const float*)d_in[0];
    float* out = (float*)d_out;
    const int B = in_sizes[0] / (IMG_H * IMG_W * 3);
    const int nbands = (IMG_W + BAND - 1) / BAND;   // 9
    dim3 grid(nbands, IMG_H / STRIPH, B);
    dim3 block(64, 1, 1);
    edge_wave_kernel<<<grid, block, 0, stream>>>(in, out);
}

// Round 12
// 167.550 us; speedup vs baseline: 1.0720x; 1.0720x over previous
//
#include <hip/hip_runtime.h>

#define IMG_H 512
#define IMG_W 512
#define BAND   58   // output columns per wave (64 lanes - 2*3 halo)
#define STRIPH 16   // output rows per wave
#define WPB    4    // independent waves (strips) per block

__global__ __launch_bounds__(256)
void edge_wave_kernel(const float* __restrict__ in, float* __restrict__ out) {
    const int band = blockIdx.x;
    const int wid  = threadIdx.x >> 6;
    const int lane = threadIdx.x & 63;
    const int y0   = (blockIdx.y * WPB + wid) * STRIPH;
    const int img  = blockIdx.z;

    // column handled by this lane (gray space), image-edge reflected, fixed per lane
    const int col = band * BAND - 3 + lane;
    int rc = col < 0 ? -col : col;
    rc = rc >= IMG_W ? (2 * IMG_W - 2 - rc) : rc;
    const bool valid = (lane >= 3) && (lane < 3 + BAND) && (col < IMG_W);

    const float* src = in + (size_t)img * (IMG_H * IMG_W * 3) + (size_t)rc * 3;
    float* dst = out + (size_t)img * (IMG_H * IMG_W) + (size_t)y0 * IMG_W + col;

    const float wr = 0.2989f, wg = 0.5870f, wb = 0.1140f;
    // composed (sobel-smooth ∘ gauss) symmetric 7-tap: [c3,c2,c1,c0,c1,c2,c3]
    const float c0 = 1.05192494f, c1 = 0.87992161f, c2 = 0.47403752f, c3 = 0.12007838f;
    // composed (sobel-deriv ∘ gauss) antisym 7-tap: [-a3,-a2,-a1,0,a1,a2,a3]
    const float a1 = 0.17200333f, a2 = 0.23388076f, a3 = 0.12007838f;

    float w[7];  // rolling gray window, slot = gray_row % 7 (all indices compile-time)

    // gray value for strip-local gray-row l (image row y0-3+l, reflected at image edges)
    auto grayrow = [&](int l) -> float {
        int y = y0 - 3 + l;
        y = y < 0 ? -y : y;
        y = y >= IMG_H ? (2 * IMG_H - 2 - y) : y;
        const float* p = src + (size_t)y * (IMG_W * 3);
        return p[0] * wr + p[1] * wg + p[2] * wb;
    };

    // emit output strip-row r; window top (gray row r) lives in slot o (compile-time)
    auto emit = [&](int r, int o) {
        const float wA = w[o % 7],       wB = w[(o + 1) % 7], wC = w[(o + 2) % 7],
                    wD = w[(o + 3) % 7], wE = w[(o + 4) % 7], wF = w[(o + 5) % 7],
                    wG = w[(o + 6) % 7];
        const float v1 = c3 * (wA + wG) + c2 * (wB + wF) + c1 * (wC + wE) + c0 * wD;
        const float v2 = a3 * (wG - wA) + a2 * (wF - wB) + a1 * (wE - wC);

        const float v1m1 = __shfl_up(v1, 1, 64), v1p1 = __shfl_down(v1, 1, 64);
        const float v1m2 = __shfl_up(v1, 2, 64), v1p2 = __shfl_down(v1, 2, 64);
        const float v1m3 = __shfl_up(v1, 3, 64), v1p3 = __shfl_down(v1, 3, 64);
        const float v2m1 = __shfl_up(v2, 1, 64), v2p1 = __shfl_down(v2, 1, 64);
        const float v2m2 = __shfl_up(v2, 2, 64), v2p2 = __shfl_down(v2, 2, 64);
        const float v2m3 = __shfl_up(v2, 3, 64), v2p3 = __shfl_down(v2, 3, 64);

        const float sx = a1 * (v1p1 - v1m1) + a2 * (v1p2 - v1m2) + a3 * (v1p3 - v1m3);
        const float sy = c0 * v2 + c1 * (v2p1 + v2m1) + c2 * (v2p2 + v2m2) + c3 * (v2p3 + v2m3);
        const float m2 = sx * sx + sy * sy;
        if (valid) dst[(size_t)r * IMG_W] = (m2 > 900.0f) ? 1.0f : 0.0f;
    };

    // warm-up: fill window with gray rows 0..6
    #pragma unroll
    for (int l = 0; l < 7; ++l) w[l] = grayrow(l);

    // steady state, fully unrolled; 1-row load lookahead ahead of each emit
    #pragma unroll
    for (int r = 0; r < STRIPH; ++r) {
        float nr = 0.0f;
        if (r + 1 < STRIPH) nr = grayrow(r + 7);   // issue next row's loads early
        emit(r, r % 7);
        if (r + 1 < STRIPH) w[r % 7] = nr;         // rotate window
    }
}

extern "C" void kernel_launch(void* const* d_in, const int* in_sizes, int n_in,
                              void* d_out, int out_size, void* d_ws, size_t ws_size,
                              hipStream_t stream) {
    const float* in = (const float*)d_in[0];
    float* out = (float*)d_out;
    const int B = in_sizes[0] / (IMG_H * IMG_W * 3);
    const int nbands = (IMG_W + BAND - 1) / BAND;     // 9
    dim3 grid(nbands, IMG_H / (STRIPH * WPB), B);     // 9 x 8 x 32
    dim3 block(256, 1, 1);
    edge_wave_kernel<<<grid, block, 0, stream>>>(in, out);
}